// Round 11
// baseline (251.271 us; speedup 1.0000x reference)
//
#include <hip/hip_runtime.h>
#include <hip/hip_bf16.h>
#include <math.h>

// Problem constants
#define NNODES 10000
#define NEDGE  160000
#define BCAP   64          // per-node bucket capacity (max degree ~40 here)
// MULT=16, NL=2, DIM=4, EDGE_DIM=32, HID=128, RANK=8, H=4, HM=4

typedef unsigned short u16;
using bf16x8 = __attribute__((ext_vector_type(8))) short;
using f32x4  = __attribute__((ext_vector_type(4))) float;

static __device__ __forceinline__ u16 f2bf(float x) {
  unsigned u = __float_as_uint(x);
  u += 0x7FFFu + ((u >> 16) & 1u);     // RNE
  return (u16)(u >> 16);
}
static __device__ __forceinline__ float bf2f(u16 h) {
  return __uint_as_float(((unsigned)h) << 16);
}
// packed RNE f32x2 -> bf16x2 (gfx950 v_cvt_pk_bf16_f32 via HIP API)
static __device__ __forceinline__ unsigned pack_bf16(float a, float b) {
  __hip_bfloat162 h = __float22bfloat162_rn(make_float2(a, b));
  return *(unsigned*)&h;               // low = a, high = b
}
// tanh-form gelu: x*sigmoid(x*(1.5957691 + 0.0713548*x^2)); |err| < 5e-4 abs.
static __device__ __forceinline__ float fast_gelu(float x) {
  float y = x * __builtin_fmaf(0.07135481283f, x * x, 1.5957691216f);
  float e = __expf(y);
  return x - x * __builtin_amdgcn_rcpf(e + 1.0f);
}

// ------ mega-setup: fill(8thr/edge) | prep_w | prep_w1 | bucket | q ---------
// LESSONS: (r1) 10.9M global f32 atomics -> never; 160K int atomics fine.
// (r2-r4) ANY VGPR-adding perturbation of the conv body tips 64->68 over the
// occupancy cliff -> conv changes must be SGPR/SALU-only. (r5) no cooperative
// launch. (r6) no serial block in a wide dispatch; no big LDS in one branch.
// (r8) per-node overhead ~5us. (r10) fill parallelization = flat -> setup is
// not the long pole; front-end model needs direct measurement.
__global__ void __launch_bounds__(256) setup_kernel(
    const float* __restrict__ kwr, const float* __restrict__ kwl,
    const float* __restrict__ vwr, const float* __restrict__ vwl,
    u16* __restrict__ Wsw,
    const float* __restrict__ kw1, const float* __restrict__ vw1,
    u16* __restrict__ W1sw,
    const float* __restrict__ f, const float* __restrict__ qw,
    const float* __restrict__ qb, float* __restrict__ q,
    const int* __restrict__ dst, const int* __restrict__ src,
    int* __restrict__ cnt, int* __restrict__ bucket,
    const float* __restrict__ ef, const float* __restrict__ b1,
    const float* __restrict__ b2, char* __restrict__ comb) {
  int b = blockIdx.x, tid = threadIdx.x;
  if (b < 5000) {                     // fill: 8 thr/edge, EDGE-ORDER comb
    int e = b * 32 + (tid >> 3);      // 0..159999 exact
    int j8 = tid & 7;
    char* rb = comb + (size_t)e * 192;
    const float* frow = f + (size_t)src[e] * 64;
    const float* be = b1 + (size_t)e * 8;          // (4,2)
    float4 bb0 = *(const float4*)&be[0];           // b[0..3]
    float4 bb1 = *(const float4*)&be[4];           // b[4..7]
    // t rows m = 2*j8, 2*j8+1  (8 threads cover 256B of frow contiguously)
    float4 a = *(const float4*)&frow[(2 * j8) * 4];
    float t0 = a.x * bb0.x + a.y * bb0.z + a.z * bb1.x + a.w * bb1.z;
    float t1 = a.x * bb0.y + a.y * bb0.w + a.z * bb1.y + a.w * bb1.w;
    float4 c = *(const float4*)&frow[(2 * j8 + 1) * 4];
    float t2a = c.x * bb0.x + c.y * bb0.z + c.z * bb1.x + c.w * bb1.z;
    float t3a = c.x * bb0.y + c.y * bb0.w + c.z * bb1.y + c.w * bb1.w;
    *(uint2*)(rb + j8 * 8) = make_uint2(pack_bf16(t0, t1), pack_bf16(t2a, t3a));
    // ef bf16 cast at +64B: thread j8 covers floats j8*4..j8*4+3
    float4 ev = *(const float4*)&ef[(size_t)e * 32 + j8 * 4];
    *(uint2*)(rb + 64 + j8 * 8) =
        make_uint2(pack_bf16(ev.x, ev.y), pack_bf16(ev.z, ev.w));
    // b2 copy at +128B (threads 0-1), dst node at +160B (thread 0)
    if (j8 < 2)
      *(float4*)(rb + 128 + j8 * 16) = *(const float4*)&b2[(size_t)e * 8 + j8 * 4];
    if (j8 == 0)
      *(int*)(rb + 160) = dst[e];
  } else if (b < 5512) {              // prep_w: 512 blocks
    int idx = (b - 5000) * 256 + tid; // 0..131071  (4 slots x 32768)
    int slot = idx >> 15;
    int w = idx & 32767;
    int j = w & 7, lane = (w >> 3) & 63, ks = (w >> 9) & 3, tg = w >> 11;
    int k   = ks * 32 + ((lane >> 4) << 3) + j;
    int col = (tg << 4) + (lane & 15);
    const float* s = (slot == 0) ? kwr : (slot == 1) ? kwl : (slot == 2) ? vwr : vwl;
    Wsw[idx] = f2bf(s[k * 256 + col]);
  } else if (b < 5544) {              // prep_w1: 32 blocks
    int idx = (b - 5512) * 256 + tid; // 0..8191 (2 slots x 4096)
    int slot = idx >> 12;
    int w = idx & 4095;
    int j = w & 7, lane = (w >> 3) & 63, nt = w >> 9;
    int k   = ((lane >> 4) << 3) + j;
    int col = (nt << 4) + (lane & 15);
    const float* s = (slot == 0) ? kw1 : vw1;
    W1sw[idx] = f2bf(s[k * 128 + col]);
  } else if (b < 6169) {              // bucket-assign: 625 blocks
    int e = (b - 5544) * 256 + tid;   // 0..159999 exact
    int n = dst[e];
    int pos = atomicAdd(&cnt[n], 1);  // cnt pre-zeroed by memset node
    bucket[n * BCAP + pos] = e;
  } else {                            // q: 625 blocks (shortest last)
    int i = (b - 6169) * 256 + tid;   // n*16 + o
    if (i >= NNODES * 16) return;
    int n = i >> 4, o = i & 15;
    const float* frow = f + (size_t)n * 64;
    float o0 = 0.f, o1 = 0.f, o2 = 0.f, o3 = 0.f;
#pragma unroll
    for (int m = 0; m < 16; ++m) {
      float w0 = qw[o * 16 + m];
      float w1 = qw[(16 + o) * 16 + m];
      float4 fv = *(const float4*)&frow[m * 4];
      o0 += w0 * fv.x;
      o1 += w1 * fv.y;
      o2 += w1 * fv.z;
      o3 += w1 * fv.w;
    }
    o0 += qb[o];
    float4 r = make_float4(o0, o1, o2, o3);
    *(float4*)(q + (size_t)i * 4) = r;
  }
}

// ---------------- merged equivariant conv (K and V in one dispatch) ---------
// Body VERBATIM round-0 (82-88us, 64 VGPR, 38% occupancy). Two SGPR-only
// additions this round (zero VGPR impact, gate on VGPR_Count==64):
// (1) pair-chunked XCD swizzle: wid=(bid&7)*625+(bid>>3) so the K and V
//     block of one tile land on the SAME XCD (round-robin had them on
//     different XCDs -> comb reread was cross-XCD L3, not L2).
// (2) s_setprio(1) around the K-loop: multiple blocks per CU sit at
//     independent phases -> MFMA-phase waves preempt staging waves (T5).
__global__ void __launch_bounds__(512) conv_fused_kernel(
    const char* __restrict__ comb,
    const u16* __restrict__ w1sw_k, const float* __restrict__ b1h_k,
    const u16* __restrict__ wswr_k, const float* __restrict__ br_k,
    const u16* __restrict__ wswl_k, const float* __restrict__ bl_k,
    const u16* __restrict__ w1sw_v, const float* __restrict__ b1h_v,
    const u16* __restrict__ wswr_v, const float* __restrict__ br_v,
    const u16* __restrict__ wswl_v, const float* __restrict__ bl_v,
    const float* __restrict__ qbuf, float* __restrict__ exs,
    u16* __restrict__ kv) {
  __shared__ alignas(16) u16 sA[64 * 136];    // H tile [edge][hid]
  __shared__ alignas(16) u16 t_s[64 * 40];    // t tile (bf16)
  __shared__ alignas(16) float b2_s[64 * 12];
  __shared__ alignas(16) float u_s[64 * 12];  // u[e][p]
  __shared__ alignas(16) float t2_pool[64 * 36]; // t2[e][r2]; overlays efs
  float* t2_s = t2_pool;
  u16*   efs  = (u16*)t2_pool;                // ef tile bf16 [edge][k] pitch 40

  int tid = threadIdx.x;
  int wave = tid >> 6, lane = tid & 63, quad = lane >> 4, l16 = lane & 15;
  // XCD-chunked work id: 5000 % 8 == 0 -> bijective (SGPR-only math)
  int wid = (blockIdx.x & 7) * 625 + (blockIdx.x >> 3);
  bool kmode = (wid & 1) == 0;
  size_t i0 = (size_t)(wid >> 1) * 64;

  const u16*   w1sw = kmode ? w1sw_k : w1sw_v;
  const float* b1h  = kmode ? b1h_k  : b1h_v;
  const u16*   wsw_r = kmode ? wswr_k : wswr_v;
  const float* br    = kmode ? br_k   : br_v;
  const u16*   wsw_l = kmode ? wswl_k : wswl_v;
  const float* bl    = kmode ? bl_k   : bl_v;

  // ---- stage tiles from comb ----
  if (tid < 256) {            // ef tile: 64 rows x 64B at +64
    int row = tid >> 2, seg = tid & 3;
    *(uint4*)&efs[row * 40 + seg * 8] =
        *(const uint4*)(comb + (i0 + row) * 192 + 64 + seg * 16);
    if (tid < 128) {          // b2 tile: 64 rows x 32B at +128
      int r2 = tid >> 1, half = tid & 1;
      *(float4*)&b2_s[r2 * 12 + half * 4] =
          *(const float4*)(comb + (i0 + r2) * 192 + 128 + half * 16);
    }
  } else {                    // t tile: 64 rows x 64B at +0
    int j = tid - 256;
    int row = j >> 2, seg = j & 3;
    *(uint4*)&t_s[row * 40 + seg * 8] =
        *(const uint4*)(comb + (i0 + row) * 192 + seg * 16);
  }
  __syncthreads();

  // ---- h-stage: wave owns hid-tile `wave` (16 cols), 4 edge tiles ----
  {
    bf16x8 aw = *(const bf16x8*)&w1sw[(size_t)(wave * 64 + lane) * 8];  // A = w1^T
    float4 bias_h = *(const float4*)&b1h[wave * 16 + quad * 4];
#pragma unroll
    for (int nt = 0; nt < 4; ++nt) {
      bf16x8 be = *(const bf16x8*)&efs[(nt * 16 + l16) * 40 + quad * 8]; // B = ef^T
      f32x4 acch = __builtin_amdgcn_mfma_f32_16x16x32_bf16(aw, be, (f32x4){0.f, 0.f, 0.f, 0.f}, 0, 0, 0);
      unsigned p0 = pack_bf16(fast_gelu(acch[0] + bias_h.x), fast_gelu(acch[1] + bias_h.y));
      unsigned p1 = pack_bf16(fast_gelu(acch[2] + bias_h.z), fast_gelu(acch[3] + bias_h.w));
      *(uint2*)&sA[(nt * 16 + l16) * 136 + wave * 16 + quad * 4] = make_uint2(p0, p1);
    }
  }
  __syncthreads();

  // ---- K-loop: transposed GEMMs (A = weights, B = H), zero-seeded accs ----
  f32x4 accr[2][4], accl[2][4];
#pragma unroll
  for (int mtl = 0; mtl < 2; ++mtl)
#pragma unroll
    for (int nt = 0; nt < 4; ++nt) {
      accr[mtl][nt] = (f32x4){0.f, 0.f, 0.f, 0.f};
      accl[mtl][nt] = (f32x4){0.f, 0.f, 0.f, 0.f};
    }
  __builtin_amdgcn_s_setprio(1);
#pragma unroll
  for (int ks = 0; ks < 4; ++ks) {
    bf16x8 bfrag[4];
#pragma unroll
    for (int nt = 0; nt < 4; ++nt)
      bfrag[nt] = *(const bf16x8*)&sA[(nt * 16 + l16) * 136 + ks * 32 + quad * 8];
#pragma unroll
    for (int mtl = 0; mtl < 2; ++mtl) {
      int mtg = wave * 2 + mtl;
      bf16x8 ar = *(const bf16x8*)&wsw_r[(size_t)((mtg * 4 + ks) * 64 + lane) * 8];
      bf16x8 al = *(const bf16x8*)&wsw_l[(size_t)((mtg * 4 + ks) * 64 + lane) * 8];
#pragma unroll
      for (int nt = 0; nt < 4; ++nt) {
        accr[mtl][nt] = __builtin_amdgcn_mfma_f32_16x16x32_bf16(ar, bfrag[nt], accr[mtl][nt], 0, 0, 0);
        accl[mtl][nt] = __builtin_amdgcn_mfma_f32_16x16x32_bf16(al, bfrag[nt], accl[mtl][nt], 0, 0, 0);
      }
    }
  }
  __builtin_amdgcn_s_setprio(0);

  // ---- bias preloads: weight-col = (2w+mtl)*16 + 4q + r ----
  float4 brv[2], blv[2];
#pragma unroll
  for (int mtl = 0; mtl < 2; ++mtl) {
    int colb = (wave * 2 + mtl) * 16 + quad * 4;
    brv[mtl] = *(const float4*)&br[colb];
    blv[mtl] = *(const float4*)&bl[colb];
  }

  // ---- right epilogue: u[e, p=wave] = sum_c (right+br)*t ----
#pragma unroll
  for (int nt = 0; nt < 4; ++nt) {
    int e = nt * 16 + l16;
    ushort4 ta = *(const ushort4*)&t_s[e * 40 + 4 * quad];        // c: mtl=0
    ushort4 tb = *(const ushort4*)&t_s[e * 40 + 16 + 4 * quad];   // c: mtl=1
    float s = (accr[0][nt][0] + brv[0].x) * bf2f(ta.x)
            + (accr[0][nt][1] + brv[0].y) * bf2f(ta.y)
            + (accr[0][nt][2] + brv[0].z) * bf2f(ta.z)
            + (accr[0][nt][3] + brv[0].w) * bf2f(ta.w)
            + (accr[1][nt][0] + brv[1].x) * bf2f(tb.x)
            + (accr[1][nt][1] + brv[1].y) * bf2f(tb.y)
            + (accr[1][nt][2] + brv[1].z) * bf2f(tb.z)
            + (accr[1][nt][3] + brv[1].w) * bf2f(tb.w);
    s += __shfl_xor(s, 16);
    s += __shfl_xor(s, 32);
    if (quad == 0) u_s[e * 12 + wave] = s;
  }
  __syncthreads();   // u_s ready; efs reads long done -> t2_s overlay safe

  // ---- left epilogue: t2[e, r2] = sum_p (left+bl)*u ----
#pragma unroll
  for (int nt = 0; nt < 4; ++nt) {
    int e = nt * 16 + l16;
    float4 uv = *(const float4*)&u_s[e * 12 + 4 * (quad & 1)];
#pragma unroll
    for (int mtl = 0; mtl < 2; ++mtl) {
      float s = (accl[mtl][nt][0] + blv[mtl].x) * uv.x
              + (accl[mtl][nt][1] + blv[mtl].y) * uv.y
              + (accl[mtl][nt][2] + blv[mtl].z) * uv.z
              + (accl[mtl][nt][3] + blv[mtl].w) * uv.w;
      s += __shfl_xor(s, 16);                    // combine p halves (q^1)
      if ((quad & 1) == 0)
        t2_s[e * 36 + 4 * wave + 2 * mtl + (quad >> 1)] = s;
    }
  }
  __syncthreads();

  // ---- final stage: thread -> (e = tid>>3, j = tid&7), elems j*8..j*8+7 ----
  {
    int e = tid >> 3, j = tid & 7;
    float4 t2 = *(const float4*)&t2_s[e * 36 + 4 * j];   // r2 = 4j..4j+3
    float4 b2a = *(const float4*)&b2_s[e * 12 + 0];
    float4 b2b = *(const float4*)&b2_s[e * 12 + 4];
    float v0 = t2.x * b2a.x + t2.y * b2b.x;   // m=2j,   d=0..3
    float v1 = t2.x * b2a.y + t2.y * b2b.y;
    float v2 = t2.x * b2a.z + t2.y * b2b.z;
    float v3 = t2.x * b2a.w + t2.y * b2b.w;
    float v4 = t2.z * b2a.x + t2.w * b2b.x;   // m=2j+1, d=0..3
    float v5 = t2.z * b2a.y + t2.w * b2b.y;
    float v6 = t2.z * b2a.z + t2.w * b2b.z;
    float v7 = t2.z * b2a.w + t2.w * b2b.w;
    if (kmode) {
      // K mode: head (j>>1) half-dot with q, pair-combine, exp, store ex
      int n = *(const int*)(comb + (i0 + e) * 192 + 160);
      const float* qr = qbuf + (size_t)n * 64 + j * 8;
      float4 qa = *(const float4*)&qr[0];
      float4 qc = *(const float4*)&qr[4];
      float s = v0 * qa.x + v1 * qa.y + v2 * qa.z + v3 * qa.w
              + v4 * qc.x + v5 * qc.y + v6 * qc.z + v7 * qc.w;
      s += __shfl_xor(s, 1);                     // combine the two half-heads
      if ((j & 1) == 0)
        exs[(i0 + e) * 4 + (j >> 1)] = __expf(s * 0.25f);
    } else {
      // V mode: pack bf16 kv row
      unsigned q0 = pack_bf16(v0, v1);
      unsigned q1 = pack_bf16(v2, v3);
      unsigned q2 = pack_bf16(v4, v5);
      unsigned q3 = pack_bf16(v6, v7);
      *(uint4*)&kv[(i0 + e) * 64 + j * 8] = make_uint4(q0, q1, q2, q3);
    }
  }
}

// ---------------- attention gather: vectorized two-edge-per-wave ------------
// lanes 0-31 = edge A, lanes 32-63 = edge B; each lane loads one uint
// (2 bf16 = output positions 2*l32, 2*l32+1). Halves combined with
// shfl_xor(32); den per-head (head = l32>>3). (r9: validated, part of -13us)
__global__ void __launch_bounds__(256) attn_gather_kernel(
    const float* __restrict__ exs, const u16* __restrict__ kvv,
    const int* __restrict__ cnt, const int* __restrict__ bucket,
    float* __restrict__ outp) {
  int tid = threadIdx.x;
  int node = blockIdx.x * 4 + (tid >> 6);        // grid 2500 * 4 = NNODES
  int lane = tid & 63;
  int half = lane >> 5;                          // 0: edge A, 1: edge B
  int l32 = lane & 31;                           // covers elems 2*l32, 2*l32+1
  int h = l32 >> 3;                              // head of both elems
  int end = cnt[node];
  const int* bk = bucket + (size_t)node * BCAP;
  float nx = 0.f, ny = 0.f, den = 0.f;
  int idx = 0;
  for (; idx + 4 <= end; idx += 4) {             // 4 edges: 2 indep chains
    int e0 = bk[idx + half];
    int e1 = bk[idx + 2 + half];
    float x0 = exs[(size_t)e0 * 4 + h];
    float x1 = exs[(size_t)e1 * 4 + h];
    unsigned p0 = *(const unsigned*)&kvv[(size_t)e0 * 64 + l32 * 2];
    unsigned p1 = *(const unsigned*)&kvv[(size_t)e1 * 64 + l32 * 2];
    nx += x0 * bf2f((u16)(p0 & 0xFFFF)) + x1 * bf2f((u16)(p1 & 0xFFFF));
    ny += x0 * bf2f((u16)(p0 >> 16))    + x1 * bf2f((u16)(p1 >> 16));
    den += x0 + x1;
  }
  for (; idx + 2 <= end; idx += 2) {             // 2 edges
    int e0 = bk[idx + half];
    float x0 = exs[(size_t)e0 * 4 + h];
    unsigned p0 = *(const unsigned*)&kvv[(size_t)e0 * 64 + l32 * 2];
    nx += x0 * bf2f((u16)(p0 & 0xFFFF));
    ny += x0 * bf2f((u16)(p0 >> 16));
    den += x0;
  }
  if (idx < end && half == 0) {                  // odd tail: half A only
    int e0 = bk[idx];
    float x0 = exs[(size_t)e0 * 4 + h];
    unsigned p0 = *(const unsigned*)&kvv[(size_t)e0 * 64 + l32 * 2];
    nx += x0 * bf2f((u16)(p0 & 0xFFFF));
    ny += x0 * bf2f((u16)(p0 >> 16));
    den += x0;
  }
  // combine the two half-wave edge streams
  nx  += __shfl_xor(nx, 32);
  ny  += __shfl_xor(ny, 32);
  den += __shfl_xor(den, 32);
  if (half == 0) {
    float r = 1.0f / fmaxf(den, 1e-9f);
    float2 o = make_float2(nx * r, ny * r);
    *(float2*)&outp[(size_t)node * 64 + l32 * 2] = o;
  }
}

extern "C" void kernel_launch(void* const* d_in, const int* in_sizes, int n_in,
                              void* d_out, int out_size, void* d_ws, size_t ws_size,
                              hipStream_t stream) {
  const float* b1  = (const float*)d_in[0];
  const float* b2  = (const float*)d_in[1];
  const float* ef  = (const float*)d_in[2];
  const float* f   = (const float*)d_in[3];
  const int*   src = (const int*)d_in[4];
  const int*   dst = (const int*)d_in[5];
  const float* qw  = (const float*)d_in[6];
  const float* qb  = (const float*)d_in[7];
  const float* kw1 = (const float*)d_in[8];
  const float* kb1 = (const float*)d_in[9];
  const float* kwl = (const float*)d_in[10];
  const float* kbl = (const float*)d_in[11];
  const float* kwr = (const float*)d_in[12];
  const float* kbr = (const float*)d_in[13];
  const float* vw1 = (const float*)d_in[14];
  const float* vb1 = (const float*)d_in[15];
  const float* vwl = (const float*)d_in[16];
  const float* vbl = (const float*)d_in[17];
  const float* vwr = (const float*)d_in[18];
  const float* vbr = (const float*)d_in[19];
  float* outp = (float*)d_out;

  // workspace layout
  char* ws = (char*)d_ws;
  size_t off = 0;
  auto alloc = [&](size_t bytes) {
    char* p = ws + off;
    off += (bytes + 511) & ~(size_t)511;
    return p;
  };
  u16*   Wsw  = (u16*)  alloc((size_t)4 * 32768 * 2);
  u16*   W1sw = (u16*)  alloc((size_t)2 * 4096 * 2);
  char*  comb = (char*) alloc((size_t)NEDGE * 192);
  u16*   kvv  = (u16*)  alloc((size_t)NEDGE * 64 * 2);
  float* exb  = (float*)alloc((size_t)NEDGE * 4 * 4);
  float* qbuf = (float*)alloc((size_t)NNODES * 64 * 4);
  int*   cnt    = (int*)alloc((size_t)NNODES * 4);
  int*   bucket = (int*)alloc((size_t)NNODES * BCAP * 4);

  // zero cnt (graph memset node), then the 5-branch mega-setup:
  // fill(8thr/edge) | prep_w | prep_w1 | bucket-assign | q
  hipMemsetAsync(cnt, 0, (size_t)NNODES * 4, stream);
  setup_kernel<<<6794, 256, 0, stream>>>(kwr, kwl, vwr, vwl, Wsw,
                                         kw1, vw1, W1sw,
                                         f, qw, qb, qbuf,
                                         dst, src, cnt, bucket,
                                         ef, b1, b2, comb);

  // merged conv: even wid = K (emit ex), odd wid = V (emit kv rows);
  // blockIdx -> wid via pair-chunked XCD swizzle (same-XCD K/V pairs)
  conv_fused_kernel<<<5000, 512, 0, stream>>>(comb,
                                              W1sw + 0 * 4096, kb1,
                                              Wsw + 0 * 32768, kbr,
                                              Wsw + 1 * 32768, kbl,
                                              W1sw + 1 * 4096, vb1,
                                              Wsw + 2 * 32768, vbr,
                                              Wsw + 3 * 32768, vbl,
                                              qbuf, exb, kvv);

  // attention: vectorized streaming weighted sum via per-node bucket list
  attn_gather_kernel<<<2500, 256, 0, stream>>>(exb, kvv, cnt, bucket, outp);
}

// Round 12
// 219.665 us; speedup vs baseline: 1.1439x; 1.1439x over previous
//
#include <hip/hip_runtime.h>
#include <hip/hip_bf16.h>
#include <math.h>

// Problem constants
#define NNODES 10000
#define NEDGE  160000
#define BCAP   64          // per-node bucket capacity (max degree ~40 here)
// MULT=16, NL=2, DIM=4, EDGE_DIM=32, HID=128, RANK=8, H=4, HM=4

typedef unsigned short u16;
using bf16x8 = __attribute__((ext_vector_type(8))) short;
using f32x4  = __attribute__((ext_vector_type(4))) float;

static __device__ __forceinline__ u16 f2bf(float x) {
  unsigned u = __float_as_uint(x);
  u += 0x7FFFu + ((u >> 16) & 1u);     // RNE
  return (u16)(u >> 16);
}
static __device__ __forceinline__ float bf2f(u16 h) {
  return __uint_as_float(((unsigned)h) << 16);
}
// packed RNE f32x2 -> bf16x2 (gfx950 v_cvt_pk_bf16_f32 via HIP API)
static __device__ __forceinline__ unsigned pack_bf16(float a, float b) {
  __hip_bfloat162 h = __float22bfloat162_rn(make_float2(a, b));
  return *(unsigned*)&h;               // low = a, high = b
}
// tanh-form gelu: x*sigmoid(x*(1.5957691 + 0.0713548*x^2)); |err| < 5e-4 abs.
static __device__ __forceinline__ float fast_gelu(float x) {
  float y = x * __builtin_fmaf(0.07135481283f, x * x, 1.5957691216f);
  float e = __expf(y);
  return x - x * __builtin_amdgcn_rcpf(e + 1.0f);
}

// ------ mega-setup: fill(8thr/edge) | prep_w | prep_w1 | bucket | q ---------
// LESSONS: (r1) 10.9M global f32 atomics -> never; 160K int atomics fine.
// (r2-r4, r11) ANY perturbation of the conv body risks the 64->68+ VGPR
// occupancy cliff -> one change at a time, gate on VGPR_Count==64.
// (r5) no cooperative launch. (r6) no serial block in a wide dispatch.
// (r8) per-node overhead ~5us. (r10) fill parallelization = flat.
// (r11) pair-chunked XCD swizzle DID cut FETCH 39->27.5MB (L2-local K/V
// pairs) but bundled s_setprio pushed VGPR to 72 -> this round: swizzle
// ONLY, setprio removed (strict A/B).
__global__ void __launch_bounds__(256) setup_kernel(
    const float* __restrict__ kwr, const float* __restrict__ kwl,
    const float* __restrict__ vwr, const float* __restrict__ vwl,
    u16* __restrict__ Wsw,
    const float* __restrict__ kw1, const float* __restrict__ vw1,
    u16* __restrict__ W1sw,
    const float* __restrict__ f, const float* __restrict__ qw,
    const float* __restrict__ qb, float* __restrict__ q,
    const int* __restrict__ dst, const int* __restrict__ src,
    int* __restrict__ cnt, int* __restrict__ bucket,
    const float* __restrict__ ef, const float* __restrict__ b1,
    const float* __restrict__ b2, char* __restrict__ comb) {
  int b = blockIdx.x, tid = threadIdx.x;
  if (b < 5000) {                     // fill: 8 thr/edge, EDGE-ORDER comb
    int e = b * 32 + (tid >> 3);      // 0..159999 exact
    int j8 = tid & 7;
    char* rb = comb + (size_t)e * 192;
    const float* frow = f + (size_t)src[e] * 64;
    const float* be = b1 + (size_t)e * 8;          // (4,2)
    float4 bb0 = *(const float4*)&be[0];           // b[0..3]
    float4 bb1 = *(const float4*)&be[4];           // b[4..7]
    // t rows m = 2*j8, 2*j8+1  (8 threads cover 256B of frow contiguously)
    float4 a = *(const float4*)&frow[(2 * j8) * 4];
    float t0 = a.x * bb0.x + a.y * bb0.z + a.z * bb1.x + a.w * bb1.z;
    float t1 = a.x * bb0.y + a.y * bb0.w + a.z * bb1.y + a.w * bb1.w;
    float4 c = *(const float4*)&frow[(2 * j8 + 1) * 4];
    float t2a = c.x * bb0.x + c.y * bb0.z + c.z * bb1.x + c.w * bb1.z;
    float t3a = c.x * bb0.y + c.y * bb0.w + c.z * bb1.y + c.w * bb1.w;
    *(uint2*)(rb + j8 * 8) = make_uint2(pack_bf16(t0, t1), pack_bf16(t2a, t3a));
    // ef bf16 cast at +64B: thread j8 covers floats j8*4..j8*4+3
    float4 ev = *(const float4*)&ef[(size_t)e * 32 + j8 * 4];
    *(uint2*)(rb + 64 + j8 * 8) =
        make_uint2(pack_bf16(ev.x, ev.y), pack_bf16(ev.z, ev.w));
    // b2 copy at +128B (threads 0-1), dst node at +160B (thread 0)
    if (j8 < 2)
      *(float4*)(rb + 128 + j8 * 16) = *(const float4*)&b2[(size_t)e * 8 + j8 * 4];
    if (j8 == 0)
      *(int*)(rb + 160) = dst[e];
  } else if (b < 5512) {              // prep_w: 512 blocks
    int idx = (b - 5000) * 256 + tid; // 0..131071  (4 slots x 32768)
    int slot = idx >> 15;
    int w = idx & 32767;
    int j = w & 7, lane = (w >> 3) & 63, ks = (w >> 9) & 3, tg = w >> 11;
    int k   = ks * 32 + ((lane >> 4) << 3) + j;
    int col = (tg << 4) + (lane & 15);
    const float* s = (slot == 0) ? kwr : (slot == 1) ? kwl : (slot == 2) ? vwr : vwl;
    Wsw[idx] = f2bf(s[k * 256 + col]);
  } else if (b < 5544) {              // prep_w1: 32 blocks
    int idx = (b - 5512) * 256 + tid; // 0..8191 (2 slots x 4096)
    int slot = idx >> 12;
    int w = idx & 4095;
    int j = w & 7, lane = (w >> 3) & 63, nt = w >> 9;
    int k   = ((lane >> 4) << 3) + j;
    int col = (nt << 4) + (lane & 15);
    const float* s = (slot == 0) ? kw1 : vw1;
    W1sw[idx] = f2bf(s[k * 128 + col]);
  } else if (b < 6169) {              // bucket-assign: 625 blocks
    int e = (b - 5544) * 256 + tid;   // 0..159999 exact
    int n = dst[e];
    int pos = atomicAdd(&cnt[n], 1);  // cnt pre-zeroed by memset node
    bucket[n * BCAP + pos] = e;
  } else {                            // q: 625 blocks (shortest last)
    int i = (b - 6169) * 256 + tid;   // n*16 + o
    if (i >= NNODES * 16) return;
    int n = i >> 4, o = i & 15;
    const float* frow = f + (size_t)n * 64;
    float o0 = 0.f, o1 = 0.f, o2 = 0.f, o3 = 0.f;
#pragma unroll
    for (int m = 0; m < 16; ++m) {
      float w0 = qw[o * 16 + m];
      float w1 = qw[(16 + o) * 16 + m];
      float4 fv = *(const float4*)&frow[m * 4];
      o0 += w0 * fv.x;
      o1 += w1 * fv.y;
      o2 += w1 * fv.z;
      o3 += w1 * fv.w;
    }
    o0 += qb[o];
    float4 r = make_float4(o0, o1, o2, o3);
    *(float4*)(q + (size_t)i * 4) = r;
  }
}

// ---------------- merged equivariant conv (K and V in one dispatch) ---------
// Body VERBATIM round-0/round-10 (84.9us, 64 VGPR, 38% occupancy). ONE
// change vs r10: pair-chunked XCD swizzle wid=(bid&7)*625+(bid>>3) so the
// K and V block of one tile land on the SAME XCD (r11 proved FETCH
// 39->27.5MB). NO s_setprio (r11: it pushed VGPR 64->72, occupancy cliff).
// GATE: if VGPR_Count != 64, revert the swizzle next round.
__global__ void __launch_bounds__(512) conv_fused_kernel(
    const char* __restrict__ comb,
    const u16* __restrict__ w1sw_k, const float* __restrict__ b1h_k,
    const u16* __restrict__ wswr_k, const float* __restrict__ br_k,
    const u16* __restrict__ wswl_k, const float* __restrict__ bl_k,
    const u16* __restrict__ w1sw_v, const float* __restrict__ b1h_v,
    const u16* __restrict__ wswr_v, const float* __restrict__ br_v,
    const u16* __restrict__ wswl_v, const float* __restrict__ bl_v,
    const float* __restrict__ qbuf, float* __restrict__ exs,
    u16* __restrict__ kv) {
  __shared__ alignas(16) u16 sA[64 * 136];    // H tile [edge][hid]
  __shared__ alignas(16) u16 t_s[64 * 40];    // t tile (bf16)
  __shared__ alignas(16) float b2_s[64 * 12];
  __shared__ alignas(16) float u_s[64 * 12];  // u[e][p]
  __shared__ alignas(16) float t2_pool[64 * 36]; // t2[e][r2]; overlays efs
  float* t2_s = t2_pool;
  u16*   efs  = (u16*)t2_pool;                // ef tile bf16 [edge][k] pitch 40

  int tid = threadIdx.x;
  int wave = tid >> 6, lane = tid & 63, quad = lane >> 4, l16 = lane & 15;
  // XCD-chunked work id: 5000 % 8 == 0 -> bijective (scalar math only)
  int wid = (blockIdx.x & 7) * 625 + (blockIdx.x >> 3);
  bool kmode = (wid & 1) == 0;
  size_t i0 = (size_t)(wid >> 1) * 64;

  const u16*   w1sw = kmode ? w1sw_k : w1sw_v;
  const float* b1h  = kmode ? b1h_k  : b1h_v;
  const u16*   wsw_r = kmode ? wswr_k : wswr_v;
  const float* br    = kmode ? br_k   : br_v;
  const u16*   wsw_l = kmode ? wswl_k : wswl_v;
  const float* bl    = kmode ? bl_k   : bl_v;

  // ---- stage tiles from comb ----
  if (tid < 256) {            // ef tile: 64 rows x 64B at +64
    int row = tid >> 2, seg = tid & 3;
    *(uint4*)&efs[row * 40 + seg * 8] =
        *(const uint4*)(comb + (i0 + row) * 192 + 64 + seg * 16);
    if (tid < 128) {          // b2 tile: 64 rows x 32B at +128
      int r2 = tid >> 1, half = tid & 1;
      *(float4*)&b2_s[r2 * 12 + half * 4] =
          *(const float4*)(comb + (i0 + r2) * 192 + 128 + half * 16);
    }
  } else {                    // t tile: 64 rows x 64B at +0
    int j = tid - 256;
    int row = j >> 2, seg = j & 3;
    *(uint4*)&t_s[row * 40 + seg * 8] =
        *(const uint4*)(comb + (i0 + row) * 192 + seg * 16);
  }
  __syncthreads();

  // ---- h-stage: wave owns hid-tile `wave` (16 cols), 4 edge tiles ----
  {
    bf16x8 aw = *(const bf16x8*)&w1sw[(size_t)(wave * 64 + lane) * 8];  // A = w1^T
    float4 bias_h = *(const float4*)&b1h[wave * 16 + quad * 4];
#pragma unroll
    for (int nt = 0; nt < 4; ++nt) {
      bf16x8 be = *(const bf16x8*)&efs[(nt * 16 + l16) * 40 + quad * 8]; // B = ef^T
      f32x4 acch = __builtin_amdgcn_mfma_f32_16x16x32_bf16(aw, be, (f32x4){0.f, 0.f, 0.f, 0.f}, 0, 0, 0);
      unsigned p0 = pack_bf16(fast_gelu(acch[0] + bias_h.x), fast_gelu(acch[1] + bias_h.y));
      unsigned p1 = pack_bf16(fast_gelu(acch[2] + bias_h.z), fast_gelu(acch[3] + bias_h.w));
      *(uint2*)&sA[(nt * 16 + l16) * 136 + wave * 16 + quad * 4] = make_uint2(p0, p1);
    }
  }
  __syncthreads();

  // ---- K-loop: transposed GEMMs (A = weights, B = H), zero-seeded accs ----
  f32x4 accr[2][4], accl[2][4];
#pragma unroll
  for (int mtl = 0; mtl < 2; ++mtl)
#pragma unroll
    for (int nt = 0; nt < 4; ++nt) {
      accr[mtl][nt] = (f32x4){0.f, 0.f, 0.f, 0.f};
      accl[mtl][nt] = (f32x4){0.f, 0.f, 0.f, 0.f};
    }
#pragma unroll
  for (int ks = 0; ks < 4; ++ks) {
    bf16x8 bfrag[4];
#pragma unroll
    for (int nt = 0; nt < 4; ++nt)
      bfrag[nt] = *(const bf16x8*)&sA[(nt * 16 + l16) * 136 + ks * 32 + quad * 8];
#pragma unroll
    for (int mtl = 0; mtl < 2; ++mtl) {
      int mtg = wave * 2 + mtl;
      bf16x8 ar = *(const bf16x8*)&wsw_r[(size_t)((mtg * 4 + ks) * 64 + lane) * 8];
      bf16x8 al = *(const bf16x8*)&wsw_l[(size_t)((mtg * 4 + ks) * 64 + lane) * 8];
#pragma unroll
      for (int nt = 0; nt < 4; ++nt) {
        accr[mtl][nt] = __builtin_amdgcn_mfma_f32_16x16x32_bf16(ar, bfrag[nt], accr[mtl][nt], 0, 0, 0);
        accl[mtl][nt] = __builtin_amdgcn_mfma_f32_16x16x32_bf16(al, bfrag[nt], accl[mtl][nt], 0, 0, 0);
      }
    }
  }

  // ---- bias preloads: weight-col = (2w+mtl)*16 + 4q + r ----
  float4 brv[2], blv[2];
#pragma unroll
  for (int mtl = 0; mtl < 2; ++mtl) {
    int colb = (wave * 2 + mtl) * 16 + quad * 4;
    brv[mtl] = *(const float4*)&br[colb];
    blv[mtl] = *(const float4*)&bl[colb];
  }

  // ---- right epilogue: u[e, p=wave] = sum_c (right+br)*t ----
#pragma unroll
  for (int nt = 0; nt < 4; ++nt) {
    int e = nt * 16 + l16;
    ushort4 ta = *(const ushort4*)&t_s[e * 40 + 4 * quad];        // c: mtl=0
    ushort4 tb = *(const ushort4*)&t_s[e * 40 + 16 + 4 * quad];   // c: mtl=1
    float s = (accr[0][nt][0] + brv[0].x) * bf2f(ta.x)
            + (accr[0][nt][1] + brv[0].y) * bf2f(ta.y)
            + (accr[0][nt][2] + brv[0].z) * bf2f(ta.z)
            + (accr[0][nt][3] + brv[0].w) * bf2f(ta.w)
            + (accr[1][nt][0] + brv[1].x) * bf2f(tb.x)
            + (accr[1][nt][1] + brv[1].y) * bf2f(tb.y)
            + (accr[1][nt][2] + brv[1].z) * bf2f(tb.z)
            + (accr[1][nt][3] + brv[1].w) * bf2f(tb.w);
    s += __shfl_xor(s, 16);
    s += __shfl_xor(s, 32);
    if (quad == 0) u_s[e * 12 + wave] = s;
  }
  __syncthreads();   // u_s ready; efs reads long done -> t2_s overlay safe

  // ---- left epilogue: t2[e, r2] = sum_p (left+bl)*u ----
#pragma unroll
  for (int nt = 0; nt < 4; ++nt) {
    int e = nt * 16 + l16;
    float4 uv = *(const float4*)&u_s[e * 12 + 4 * (quad & 1)];
#pragma unroll
    for (int mtl = 0; mtl < 2; ++mtl) {
      float s = (accl[mtl][nt][0] + blv[mtl].x) * uv.x
              + (accl[mtl][nt][1] + blv[mtl].y) * uv.y
              + (accl[mtl][nt][2] + blv[mtl].z) * uv.z
              + (accl[mtl][nt][3] + blv[mtl].w) * uv.w;
      s += __shfl_xor(s, 16);                    // combine p halves (q^1)
      if ((quad & 1) == 0)
        t2_s[e * 36 + 4 * wave + 2 * mtl + (quad >> 1)] = s;
    }
  }
  __syncthreads();

  // ---- final stage: thread -> (e = tid>>3, j = tid&7), elems j*8..j*8+7 ----
  {
    int e = tid >> 3, j = tid & 7;
    float4 t2 = *(const float4*)&t2_s[e * 36 + 4 * j];   // r2 = 4j..4j+3
    float4 b2a = *(const float4*)&b2_s[e * 12 + 0];
    float4 b2b = *(const float4*)&b2_s[e * 12 + 4];
    float v0 = t2.x * b2a.x + t2.y * b2b.x;   // m=2j,   d=0..3
    float v1 = t2.x * b2a.y + t2.y * b2b.y;
    float v2 = t2.x * b2a.z + t2.y * b2b.z;
    float v3 = t2.x * b2a.w + t2.y * b2b.w;
    float v4 = t2.z * b2a.x + t2.w * b2b.x;   // m=2j+1, d=0..3
    float v5 = t2.z * b2a.y + t2.w * b2b.y;
    float v6 = t2.z * b2a.z + t2.w * b2b.z;
    float v7 = t2.z * b2a.w + t2.w * b2b.w;
    if (kmode) {
      // K mode: head (j>>1) half-dot with q, pair-combine, exp, store ex
      int n = *(const int*)(comb + (i0 + e) * 192 + 160);
      const float* qr = qbuf + (size_t)n * 64 + j * 8;
      float4 qa = *(const float4*)&qr[0];
      float4 qc = *(const float4*)&qr[4];
      float s = v0 * qa.x + v1 * qa.y + v2 * qa.z + v3 * qa.w
              + v4 * qc.x + v5 * qc.y + v6 * qc.z + v7 * qc.w;
      s += __shfl_xor(s, 1);                     // combine the two half-heads
      if ((j & 1) == 0)
        exs[(i0 + e) * 4 + (j >> 1)] = __expf(s * 0.25f);
    } else {
      // V mode: pack bf16 kv row
      unsigned q0 = pack_bf16(v0, v1);
      unsigned q1 = pack_bf16(v2, v3);
      unsigned q2 = pack_bf16(v4, v5);
      unsigned q3 = pack_bf16(v6, v7);
      *(uint4*)&kv[(i0 + e) * 64 + j * 8] = make_uint4(q0, q1, q2, q3);
    }
  }
}

// ---------------- attention gather: vectorized two-edge-per-wave ------------
// lanes 0-31 = edge A, lanes 32-63 = edge B; each lane loads one uint
// (2 bf16 = output positions 2*l32, 2*l32+1). Halves combined with
// shfl_xor(32); den per-head (head = l32>>3). (r9: validated, part of -13us)
__global__ void __launch_bounds__(256) attn_gather_kernel(
    const float* __restrict__ exs, const u16* __restrict__ kvv,
    const int* __restrict__ cnt, const int* __restrict__ bucket,
    float* __restrict__ outp) {
  int tid = threadIdx.x;
  int node = blockIdx.x * 4 + (tid >> 6);        // grid 2500 * 4 = NNODES
  int lane = tid & 63;
  int half = lane >> 5;                          // 0: edge A, 1: edge B
  int l32 = lane & 31;                           // covers elems 2*l32, 2*l32+1
  int h = l32 >> 3;                              // head of both elems
  int end = cnt[node];
  const int* bk = bucket + (size_t)node * BCAP;
  float nx = 0.f, ny = 0.f, den = 0.f;
  int idx = 0;
  for (; idx + 4 <= end; idx += 4) {             // 4 edges: 2 indep chains
    int e0 = bk[idx + half];
    int e1 = bk[idx + 2 + half];
    float x0 = exs[(size_t)e0 * 4 + h];
    float x1 = exs[(size_t)e1 * 4 + h];
    unsigned p0 = *(const unsigned*)&kvv[(size_t)e0 * 64 + l32 * 2];
    unsigned p1 = *(const unsigned*)&kvv[(size_t)e1 * 64 + l32 * 2];
    nx += x0 * bf2f((u16)(p0 & 0xFFFF)) + x1 * bf2f((u16)(p1 & 0xFFFF));
    ny += x0 * bf2f((u16)(p0 >> 16))    + x1 * bf2f((u16)(p1 >> 16));
    den += x0 + x1;
  }
  for (; idx + 2 <= end; idx += 2) {             // 2 edges
    int e0 = bk[idx + half];
    float x0 = exs[(size_t)e0 * 4 + h];
    unsigned p0 = *(const unsigned*)&kvv[(size_t)e0 * 64 + l32 * 2];
    nx += x0 * bf2f((u16)(p0 & 0xFFFF));
    ny += x0 * bf2f((u16)(p0 >> 16));
    den += x0;
  }
  if (idx < end && half == 0) {                  // odd tail: half A only
    int e0 = bk[idx];
    float x0 = exs[(size_t)e0 * 4 + h];
    unsigned p0 = *(const unsigned*)&kvv[(size_t)e0 * 64 + l32 * 2];
    nx += x0 * bf2f((u16)(p0 & 0xFFFF));
    ny += x0 * bf2f((u16)(p0 >> 16));
    den += x0;
  }
  // combine the two half-wave edge streams
  nx  += __shfl_xor(nx, 32);
  ny  += __shfl_xor(ny, 32);
  den += __shfl_xor(den, 32);
  if (half == 0) {
    float r = 1.0f / fmaxf(den, 1e-9f);
    float2 o = make_float2(nx * r, ny * r);
    *(float2*)&outp[(size_t)node * 64 + l32 * 2] = o;
  }
}

extern "C" void kernel_launch(void* const* d_in, const int* in_sizes, int n_in,
                              void* d_out, int out_size, void* d_ws, size_t ws_size,
                              hipStream_t stream) {
  const float* b1  = (const float*)d_in[0];
  const float* b2  = (const float*)d_in[1];
  const float* ef  = (const float*)d_in[2];
  const float* f   = (const float*)d_in[3];
  const int*   src = (const int*)d_in[4];
  const int*   dst = (const int*)d_in[5];
  const float* qw  = (const float*)d_in[6];
  const float* qb  = (const float*)d_in[7];
  const float* kw1 = (const float*)d_in[8];
  const float* kb1 = (const float*)d_in[9];
  const float* kwl = (const float*)d_in[10];
  const float* kbl = (const float*)d_in[11];
  const float* kwr = (const float*)d_in[12];
  const float* kbr = (const float*)d_in[13];
  const float* vw1 = (const float*)d_in[14];
  const float* vb1 = (const float*)d_in[15];
  const float* vwl = (const float*)d_in[16];
  const float* vbl = (const float*)d_in[17];
  const float* vwr = (const float*)d_in[18];
  const float* vbr = (const float*)d_in[19];
  float* outp = (float*)d_out;

  // workspace layout
  char* ws = (char*)d_ws;
  size_t off = 0;
  auto alloc = [&](size_t bytes) {
    char* p = ws + off;
    off += (bytes + 511) & ~(size_t)511;
    return p;
  };
  u16*   Wsw  = (u16*)  alloc((size_t)4 * 32768 * 2);
  u16*   W1sw = (u16*)  alloc((size_t)2 * 4096 * 2);
  char*  comb = (char*) alloc((size_t)NEDGE * 192);
  u16*   kvv  = (u16*)  alloc((size_t)NEDGE * 64 * 2);
  float* exb  = (float*)alloc((size_t)NEDGE * 4 * 4);
  float* qbuf = (float*)alloc((size_t)NNODES * 64 * 4);
  int*   cnt    = (int*)alloc((size_t)NNODES * 4);
  int*   bucket = (int*)alloc((size_t)NNODES * BCAP * 4);

  // zero cnt (graph memset node), then the 5-branch mega-setup:
  // fill(8thr/edge) | prep_w | prep_w1 | bucket-assign | q
  hipMemsetAsync(cnt, 0, (size_t)NNODES * 4, stream);
  setup_kernel<<<6794, 256, 0, stream>>>(kwr, kwl, vwr, vwl, Wsw,
                                         kw1, vw1, W1sw,
                                         f, qw, qb, qbuf,
                                         dst, src, cnt, bucket,
                                         ef, b1, b2, comb);

  // merged conv: even wid = K (emit ex), odd wid = V (emit kv rows);
  // blockIdx -> wid via pair-chunked XCD swizzle (same-XCD K/V pairs)
  conv_fused_kernel<<<5000, 512, 0, stream>>>(comb,
                                              W1sw + 0 * 4096, kb1,
                                              Wsw + 0 * 32768, kbr,
                                              Wsw + 1 * 32768, kbl,
                                              W1sw + 1 * 4096, vb1,
                                              Wsw + 2 * 32768, vbr,
                                              Wsw + 3 * 32768, vbl,
                                              qbuf, exb, kvv);

  // attention: vectorized streaming weighted sum via per-node bucket list
  attn_gather_kernel<<<2500, 256, 0, stream>>>(exb, kvv, cnt, bucket, outp);
}

// Round 13
// 218.883 us; speedup vs baseline: 1.1480x; 1.0036x over previous
//
#include <hip/hip_runtime.h>
#include <hip/hip_bf16.h>
#include <math.h>

// Problem constants
#define NNODES 10000
#define NEDGE  160000
#define BCAP   64          // per-node bucket capacity (max degree ~40 here)
// MULT=16, NL=2, DIM=4, EDGE_DIM=32, HID=128, RANK=8, H=4, HM=4

typedef unsigned short u16;
using bf16x8 = __attribute__((ext_vector_type(8))) short;
using f32x4  = __attribute__((ext_vector_type(4))) float;

static __device__ __forceinline__ u16 f2bf(float x) {
  unsigned u = __float_as_uint(x);
  u += 0x7FFFu + ((u >> 16) & 1u);     // RNE
  return (u16)(u >> 16);
}
static __device__ __forceinline__ float bf2f(u16 h) {
  return __uint_as_float(((unsigned)h) << 16);
}
// packed RNE f32x2 -> bf16x2 (gfx950 v_cvt_pk_bf16_f32 via HIP API)
static __device__ __forceinline__ unsigned pack_bf16(float a, float b) {
  __hip_bfloat162 h = __float22bfloat162_rn(make_float2(a, b));
  return *(unsigned*)&h;               // low = a, high = b
}
// tanh-form gelu: x*sigmoid(x*(1.5957691 + 0.0713548*x^2)); |err| < 5e-4 abs.
static __device__ __forceinline__ float fast_gelu(float x) {
  float y = x * __builtin_fmaf(0.07135481283f, x * x, 1.5957691216f);
  float e = __expf(y);
  return x - x * __builtin_amdgcn_rcpf(e + 1.0f);
}

// ------ mega-setup: fill(8thr/edge) | prep_w | prep_w1 | bucket | q ---------
// SESSION LESSONS (final state = round-10 optimum, 217.8us):
// (r1) 10.9M global f32 atomics = 325MB write-through -> never; 160K int ok.
// (r2-r4, r11) ANY perturbation of the conv body risks the 64->68+ VGPR
//   occupancy cliff (8->4 waves/SIMD, +40us) -> conv body is FROZEN.
// (r5) no cooperative launch under graph capture.
// (r6) no serial block inside a wide dispatch; no big LDS in one branch.
// (r8) per-dispatch overhead ~5us -> dispatch-count lever exhausted at 4.
// (r9) gather vectorization (uint loads, 2-edge/wave) = -13us.
// (r10) fill parallelization = flat (front-end not fill-bound).
// (r12) XCD pair-swizzle: FETCH 39->27.5MB PROVEN but conv is latency-bound
//   (9% HBM peak) -> traffic win, time LOSS (+4.5us) -> reverted.
__global__ void __launch_bounds__(256) setup_kernel(
    const float* __restrict__ kwr, const float* __restrict__ kwl,
    const float* __restrict__ vwr, const float* __restrict__ vwl,
    u16* __restrict__ Wsw,
    const float* __restrict__ kw1, const float* __restrict__ vw1,
    u16* __restrict__ W1sw,
    const float* __restrict__ f, const float* __restrict__ qw,
    const float* __restrict__ qb, float* __restrict__ q,
    const int* __restrict__ dst, const int* __restrict__ src,
    int* __restrict__ cnt, int* __restrict__ bucket,
    const float* __restrict__ ef, const float* __restrict__ b1,
    const float* __restrict__ b2, char* __restrict__ comb) {
  int b = blockIdx.x, tid = threadIdx.x;
  if (b < 5000) {                     // fill: 8 thr/edge, EDGE-ORDER comb
    int e = b * 32 + (tid >> 3);      // 0..159999 exact
    int j8 = tid & 7;
    char* rb = comb + (size_t)e * 192;
    const float* frow = f + (size_t)src[e] * 64;
    const float* be = b1 + (size_t)e * 8;          // (4,2)
    float4 bb0 = *(const float4*)&be[0];           // b[0..3]
    float4 bb1 = *(const float4*)&be[4];           // b[4..7]
    // t rows m = 2*j8, 2*j8+1  (8 threads cover 256B of frow contiguously)
    float4 a = *(const float4*)&frow[(2 * j8) * 4];
    float t0 = a.x * bb0.x + a.y * bb0.z + a.z * bb1.x + a.w * bb1.z;
    float t1 = a.x * bb0.y + a.y * bb0.w + a.z * bb1.y + a.w * bb1.w;
    float4 c = *(const float4*)&frow[(2 * j8 + 1) * 4];
    float t2a = c.x * bb0.x + c.y * bb0.z + c.z * bb1.x + c.w * bb1.z;
    float t3a = c.x * bb0.y + c.y * bb0.w + c.z * bb1.y + c.w * bb1.w;
    *(uint2*)(rb + j8 * 8) = make_uint2(pack_bf16(t0, t1), pack_bf16(t2a, t3a));
    // ef bf16 cast at +64B: thread j8 covers floats j8*4..j8*4+3
    float4 ev = *(const float4*)&ef[(size_t)e * 32 + j8 * 4];
    *(uint2*)(rb + 64 + j8 * 8) =
        make_uint2(pack_bf16(ev.x, ev.y), pack_bf16(ev.z, ev.w));
    // b2 copy at +128B (threads 0-1), dst node at +160B (thread 0)
    if (j8 < 2)
      *(float4*)(rb + 128 + j8 * 16) = *(const float4*)&b2[(size_t)e * 8 + j8 * 4];
    if (j8 == 0)
      *(int*)(rb + 160) = dst[e];
  } else if (b < 5512) {              // prep_w: 512 blocks
    int idx = (b - 5000) * 256 + tid; // 0..131071  (4 slots x 32768)
    int slot = idx >> 15;
    int w = idx & 32767;
    int j = w & 7, lane = (w >> 3) & 63, ks = (w >> 9) & 3, tg = w >> 11;
    int k   = ks * 32 + ((lane >> 4) << 3) + j;
    int col = (tg << 4) + (lane & 15);
    const float* s = (slot == 0) ? kwr : (slot == 1) ? kwl : (slot == 2) ? vwr : vwl;
    Wsw[idx] = f2bf(s[k * 256 + col]);
  } else if (b < 5544) {              // prep_w1: 32 blocks
    int idx = (b - 5512) * 256 + tid; // 0..8191 (2 slots x 4096)
    int slot = idx >> 12;
    int w = idx & 4095;
    int j = w & 7, lane = (w >> 3) & 63, nt = w >> 9;
    int k   = ((lane >> 4) << 3) + j;
    int col = (nt << 4) + (lane & 15);
    const float* s = (slot == 0) ? kw1 : vw1;
    W1sw[idx] = f2bf(s[k * 128 + col]);
  } else if (b < 6169) {              // bucket-assign: 625 blocks
    int e = (b - 5544) * 256 + tid;   // 0..159999 exact
    int n = dst[e];
    int pos = atomicAdd(&cnt[n], 1);  // cnt pre-zeroed by memset node
    bucket[n * BCAP + pos] = e;
  } else {                            // q: 625 blocks (shortest last)
    int i = (b - 6169) * 256 + tid;   // n*16 + o
    if (i >= NNODES * 16) return;
    int n = i >> 4, o = i & 15;
    const float* frow = f + (size_t)n * 64;
    float o0 = 0.f, o1 = 0.f, o2 = 0.f, o3 = 0.f;
#pragma unroll
    for (int m = 0; m < 16; ++m) {
      float w0 = qw[o * 16 + m];
      float w1 = qw[(16 + o) * 16 + m];
      float4 fv = *(const float4*)&frow[m * 4];
      o0 += w0 * fv.x;
      o1 += w1 * fv.y;
      o2 += w1 * fv.z;
      o3 += w1 * fv.w;
    }
    o0 += qb[o];
    float4 r = make_float4(o0, o1, o2, o3);
    *(float4*)(q + (size_t)i * 4) = r;
  }
}

// ---------------- merged equivariant conv (K and V in one dispatch) ---------
// VERBATIM round-0/round-10 kernel (measured 84.9us, 64 VGPR, 38% occupancy).
// blockIdx even -> K conv for tile (blockIdx>>1): emits ex=exp(qk/4);
// blockIdx odd  -> V conv for same tile: emits bf16 kv rows.
// FROZEN: r2-r4/r11 showed any edit crosses the 64-VGPR occupancy cliff;
// r12 showed the XCD swizzle trades time for traffic on this latency-bound
// kernel. Further conv gains require a ground-up re-tile (different register
// budget design), not incremental edits.
__global__ void __launch_bounds__(512) conv_fused_kernel(
    const char* __restrict__ comb,
    const u16* __restrict__ w1sw_k, const float* __restrict__ b1h_k,
    const u16* __restrict__ wswr_k, const float* __restrict__ br_k,
    const u16* __restrict__ wswl_k, const float* __restrict__ bl_k,
    const u16* __restrict__ w1sw_v, const float* __restrict__ b1h_v,
    const u16* __restrict__ wswr_v, const float* __restrict__ br_v,
    const u16* __restrict__ wswl_v, const float* __restrict__ bl_v,
    const float* __restrict__ qbuf, float* __restrict__ exs,
    u16* __restrict__ kv) {
  __shared__ alignas(16) u16 sA[64 * 136];    // H tile [edge][hid]
  __shared__ alignas(16) u16 t_s[64 * 40];    // t tile (bf16)
  __shared__ alignas(16) float b2_s[64 * 12];
  __shared__ alignas(16) float u_s[64 * 12];  // u[e][p]
  __shared__ alignas(16) float t2_pool[64 * 36]; // t2[e][r2]; overlays efs
  float* t2_s = t2_pool;
  u16*   efs  = (u16*)t2_pool;                // ef tile bf16 [edge][k] pitch 40

  int tid = threadIdx.x;
  int wave = tid >> 6, lane = tid & 63, quad = lane >> 4, l16 = lane & 15;
  bool kmode = (blockIdx.x & 1) == 0;
  size_t i0 = (size_t)(blockIdx.x >> 1) * 64;

  const u16*   w1sw = kmode ? w1sw_k : w1sw_v;
  const float* b1h  = kmode ? b1h_k  : b1h_v;
  const u16*   wsw_r = kmode ? wswr_k : wswr_v;
  const float* br    = kmode ? br_k   : br_v;
  const u16*   wsw_l = kmode ? wswl_k : wswl_v;
  const float* bl    = kmode ? bl_k   : bl_v;

  // ---- stage tiles from comb ----
  if (tid < 256) {            // ef tile: 64 rows x 64B at +64
    int row = tid >> 2, seg = tid & 3;
    *(uint4*)&efs[row * 40 + seg * 8] =
        *(const uint4*)(comb + (i0 + row) * 192 + 64 + seg * 16);
    if (tid < 128) {          // b2 tile: 64 rows x 32B at +128
      int r2 = tid >> 1, half = tid & 1;
      *(float4*)&b2_s[r2 * 12 + half * 4] =
          *(const float4*)(comb + (i0 + r2) * 192 + 128 + half * 16);
    }
  } else {                    // t tile: 64 rows x 64B at +0
    int j = tid - 256;
    int row = j >> 2, seg = j & 3;
    *(uint4*)&t_s[row * 40 + seg * 8] =
        *(const uint4*)(comb + (i0 + row) * 192 + seg * 16);
  }
  __syncthreads();

  // ---- h-stage: wave owns hid-tile `wave` (16 cols), 4 edge tiles ----
  {
    bf16x8 aw = *(const bf16x8*)&w1sw[(size_t)(wave * 64 + lane) * 8];  // A = w1^T
    float4 bias_h = *(const float4*)&b1h[wave * 16 + quad * 4];
#pragma unroll
    for (int nt = 0; nt < 4; ++nt) {
      bf16x8 be = *(const bf16x8*)&efs[(nt * 16 + l16) * 40 + quad * 8]; // B = ef^T
      f32x4 acch = __builtin_amdgcn_mfma_f32_16x16x32_bf16(aw, be, (f32x4){0.f, 0.f, 0.f, 0.f}, 0, 0, 0);
      unsigned p0 = pack_bf16(fast_gelu(acch[0] + bias_h.x), fast_gelu(acch[1] + bias_h.y));
      unsigned p1 = pack_bf16(fast_gelu(acch[2] + bias_h.z), fast_gelu(acch[3] + bias_h.w));
      *(uint2*)&sA[(nt * 16 + l16) * 136 + wave * 16 + quad * 4] = make_uint2(p0, p1);
    }
  }
  __syncthreads();

  // ---- K-loop: transposed GEMMs (A = weights, B = H), zero-seeded accs ----
  f32x4 accr[2][4], accl[2][4];
#pragma unroll
  for (int mtl = 0; mtl < 2; ++mtl)
#pragma unroll
    for (int nt = 0; nt < 4; ++nt) {
      accr[mtl][nt] = (f32x4){0.f, 0.f, 0.f, 0.f};
      accl[mtl][nt] = (f32x4){0.f, 0.f, 0.f, 0.f};
    }
#pragma unroll
  for (int ks = 0; ks < 4; ++ks) {
    bf16x8 bfrag[4];
#pragma unroll
    for (int nt = 0; nt < 4; ++nt)
      bfrag[nt] = *(const bf16x8*)&sA[(nt * 16 + l16) * 136 + ks * 32 + quad * 8];
#pragma unroll
    for (int mtl = 0; mtl < 2; ++mtl) {
      int mtg = wave * 2 + mtl;
      bf16x8 ar = *(const bf16x8*)&wsw_r[(size_t)((mtg * 4 + ks) * 64 + lane) * 8];
      bf16x8 al = *(const bf16x8*)&wsw_l[(size_t)((mtg * 4 + ks) * 64 + lane) * 8];
#pragma unroll
      for (int nt = 0; nt < 4; ++nt) {
        accr[mtl][nt] = __builtin_amdgcn_mfma_f32_16x16x32_bf16(ar, bfrag[nt], accr[mtl][nt], 0, 0, 0);
        accl[mtl][nt] = __builtin_amdgcn_mfma_f32_16x16x32_bf16(al, bfrag[nt], accl[mtl][nt], 0, 0, 0);
      }
    }
  }

  // ---- bias preloads: weight-col = (2w+mtl)*16 + 4q + r ----
  float4 brv[2], blv[2];
#pragma unroll
  for (int mtl = 0; mtl < 2; ++mtl) {
    int colb = (wave * 2 + mtl) * 16 + quad * 4;
    brv[mtl] = *(const float4*)&br[colb];
    blv[mtl] = *(const float4*)&bl[colb];
  }

  // ---- right epilogue: u[e, p=wave] = sum_c (right+br)*t ----
#pragma unroll
  for (int nt = 0; nt < 4; ++nt) {
    int e = nt * 16 + l16;
    ushort4 ta = *(const ushort4*)&t_s[e * 40 + 4 * quad];        // c: mtl=0
    ushort4 tb = *(const ushort4*)&t_s[e * 40 + 16 + 4 * quad];   // c: mtl=1
    float s = (accr[0][nt][0] + brv[0].x) * bf2f(ta.x)
            + (accr[0][nt][1] + brv[0].y) * bf2f(ta.y)
            + (accr[0][nt][2] + brv[0].z) * bf2f(ta.z)
            + (accr[0][nt][3] + brv[0].w) * bf2f(ta.w)
            + (accr[1][nt][0] + brv[1].x) * bf2f(tb.x)
            + (accr[1][nt][1] + brv[1].y) * bf2f(tb.y)
            + (accr[1][nt][2] + brv[1].z) * bf2f(tb.z)
            + (accr[1][nt][3] + brv[1].w) * bf2f(tb.w);
    s += __shfl_xor(s, 16);
    s += __shfl_xor(s, 32);
    if (quad == 0) u_s[e * 12 + wave] = s;
  }
  __syncthreads();   // u_s ready; efs reads long done -> t2_s overlay safe

  // ---- left epilogue: t2[e, r2] = sum_p (left+bl)*u ----
#pragma unroll
  for (int nt = 0; nt < 4; ++nt) {
    int e = nt * 16 + l16;
    float4 uv = *(const float4*)&u_s[e * 12 + 4 * (quad & 1)];
#pragma unroll
    for (int mtl = 0; mtl < 2; ++mtl) {
      float s = (accl[mtl][nt][0] + blv[mtl].x) * uv.x
              + (accl[mtl][nt][1] + blv[mtl].y) * uv.y
              + (accl[mtl][nt][2] + blv[mtl].z) * uv.z
              + (accl[mtl][nt][3] + blv[mtl].w) * uv.w;
      s += __shfl_xor(s, 16);                    // combine p halves (q^1)
      if ((quad & 1) == 0)
        t2_s[e * 36 + 4 * wave + 2 * mtl + (quad >> 1)] = s;
    }
  }
  __syncthreads();

  // ---- final stage: thread -> (e = tid>>3, j = tid&7), elems j*8..j*8+7 ----
  {
    int e = tid >> 3, j = tid & 7;
    float4 t2 = *(const float4*)&t2_s[e * 36 + 4 * j];   // r2 = 4j..4j+3
    float4 b2a = *(const float4*)&b2_s[e * 12 + 0];
    float4 b2b = *(const float4*)&b2_s[e * 12 + 4];
    float v0 = t2.x * b2a.x + t2.y * b2b.x;   // m=2j,   d=0..3
    float v1 = t2.x * b2a.y + t2.y * b2b.y;
    float v2 = t2.x * b2a.z + t2.y * b2b.z;
    float v3 = t2.x * b2a.w + t2.y * b2b.w;
    float v4 = t2.z * b2a.x + t2.w * b2b.x;   // m=2j+1, d=0..3
    float v5 = t2.z * b2a.y + t2.w * b2b.y;
    float v6 = t2.z * b2a.z + t2.w * b2b.z;
    float v7 = t2.z * b2a.w + t2.w * b2b.w;
    if (kmode) {
      // K mode: head (j>>1) half-dot with q, pair-combine, exp, store ex
      int n = *(const int*)(comb + (i0 + e) * 192 + 160);
      const float* qr = qbuf + (size_t)n * 64 + j * 8;
      float4 qa = *(const float4*)&qr[0];
      float4 qc = *(const float4*)&qr[4];
      float s = v0 * qa.x + v1 * qa.y + v2 * qa.z + v3 * qa.w
              + v4 * qc.x + v5 * qc.y + v6 * qc.z + v7 * qc.w;
      s += __shfl_xor(s, 1);                     // combine the two half-heads
      if ((j & 1) == 0)
        exs[(i0 + e) * 4 + (j >> 1)] = __expf(s * 0.25f);
    } else {
      // V mode: pack bf16 kv row
      unsigned q0 = pack_bf16(v0, v1);
      unsigned q1 = pack_bf16(v2, v3);
      unsigned q2 = pack_bf16(v4, v5);
      unsigned q3 = pack_bf16(v6, v7);
      *(uint4*)&kv[(i0 + e) * 64 + j * 8] = make_uint4(q0, q1, q2, q3);
    }
  }
}

// ---------------- attention gather: vectorized two-edge-per-wave ------------
// lanes 0-31 = edge A, lanes 32-63 = edge B; each lane loads one uint
// (2 bf16 = output positions 2*l32, 2*l32+1). Halves combined with
// shfl_xor(32); den per-head (head = l32>>3). (r9: validated, -13us)
__global__ void __launch_bounds__(256) attn_gather_kernel(
    const float* __restrict__ exs, const u16* __restrict__ kvv,
    const int* __restrict__ cnt, const int* __restrict__ bucket,
    float* __restrict__ outp) {
  int tid = threadIdx.x;
  int node = blockIdx.x * 4 + (tid >> 6);        // grid 2500 * 4 = NNODES
  int lane = tid & 63;
  int half = lane >> 5;                          // 0: edge A, 1: edge B
  int l32 = lane & 31;                           // covers elems 2*l32, 2*l32+1
  int h = l32 >> 3;                              // head of both elems
  int end = cnt[node];
  const int* bk = bucket + (size_t)node * BCAP;
  float nx = 0.f, ny = 0.f, den = 0.f;
  int idx = 0;
  for (; idx + 4 <= end; idx += 4) {             // 4 edges: 2 indep chains
    int e0 = bk[idx + half];
    int e1 = bk[idx + 2 + half];
    float x0 = exs[(size_t)e0 * 4 + h];
    float x1 = exs[(size_t)e1 * 4 + h];
    unsigned p0 = *(const unsigned*)&kvv[(size_t)e0 * 64 + l32 * 2];
    unsigned p1 = *(const unsigned*)&kvv[(size_t)e1 * 64 + l32 * 2];
    nx += x0 * bf2f((u16)(p0 & 0xFFFF)) + x1 * bf2f((u16)(p1 & 0xFFFF));
    ny += x0 * bf2f((u16)(p0 >> 16))    + x1 * bf2f((u16)(p1 >> 16));
    den += x0 + x1;
  }
  for (; idx + 2 <= end; idx += 2) {             // 2 edges
    int e0 = bk[idx + half];
    float x0 = exs[(size_t)e0 * 4 + h];
    unsigned p0 = *(const unsigned*)&kvv[(size_t)e0 * 64 + l32 * 2];
    nx += x0 * bf2f((u16)(p0 & 0xFFFF));
    ny += x0 * bf2f((u16)(p0 >> 16));
    den += x0;
  }
  if (idx < end && half == 0) {                  // odd tail: half A only
    int e0 = bk[idx];
    float x0 = exs[(size_t)e0 * 4 + h];
    unsigned p0 = *(const unsigned*)&kvv[(size_t)e0 * 64 + l32 * 2];
    nx += x0 * bf2f((u16)(p0 & 0xFFFF));
    ny += x0 * bf2f((u16)(p0 >> 16));
    den += x0;
  }
  // combine the two half-wave edge streams
  nx  += __shfl_xor(nx, 32);
  ny  += __shfl_xor(ny, 32);
  den += __shfl_xor(den, 32);
  if (half == 0) {
    float r = 1.0f / fmaxf(den, 1e-9f);
    float2 o = make_float2(nx * r, ny * r);
    *(float2*)&outp[(size_t)node * 64 + l32 * 2] = o;
  }
}

extern "C" void kernel_launch(void* const* d_in, const int* in_sizes, int n_in,
                              void* d_out, int out_size, void* d_ws, size_t ws_size,
                              hipStream_t stream) {
  const float* b1  = (const float*)d_in[0];
  const float* b2  = (const float*)d_in[1];
  const float* ef  = (const float*)d_in[2];
  const float* f   = (const float*)d_in[3];
  const int*   src = (const int*)d_in[4];
  const int*   dst = (const int*)d_in[5];
  const float* qw  = (const float*)d_in[6];
  const float* qb  = (const float*)d_in[7];
  const float* kw1 = (const float*)d_in[8];
  const float* kb1 = (const float*)d_in[9];
  const float* kwl = (const float*)d_in[10];
  const float* kbl = (const float*)d_in[11];
  const float* kwr = (const float*)d_in[12];
  const float* kbr = (const float*)d_in[13];
  const float* vw1 = (const float*)d_in[14];
  const float* vb1 = (const float*)d_in[15];
  const float* vwl = (const float*)d_in[16];
  const float* vbl = (const float*)d_in[17];
  const float* vwr = (const float*)d_in[18];
  const float* vbr = (const float*)d_in[19];
  float* outp = (float*)d_out;

  // workspace layout
  char* ws = (char*)d_ws;
  size_t off = 0;
  auto alloc = [&](size_t bytes) {
    char* p = ws + off;
    off += (bytes + 511) & ~(size_t)511;
    return p;
  };
  u16*   Wsw  = (u16*)  alloc((size_t)4 * 32768 * 2);
  u16*   W1sw = (u16*)  alloc((size_t)2 * 4096 * 2);
  char*  comb = (char*) alloc((size_t)NEDGE * 192);
  u16*   kvv  = (u16*)  alloc((size_t)NEDGE * 64 * 2);
  float* exb  = (float*)alloc((size_t)NEDGE * 4 * 4);
  float* qbuf = (float*)alloc((size_t)NNODES * 64 * 4);
  int*   cnt    = (int*)alloc((size_t)NNODES * 4);
  int*   bucket = (int*)alloc((size_t)NNODES * BCAP * 4);

  // zero cnt (graph memset node), then the 5-branch mega-setup:
  // fill(8thr/edge) | prep_w | prep_w1 | bucket-assign | q
  hipMemsetAsync(cnt, 0, (size_t)NNODES * 4, stream);
  setup_kernel<<<6794, 256, 0, stream>>>(kwr, kwl, vwr, vwl, Wsw,
                                         kw1, vw1, W1sw,
                                         f, qw, qb, qbuf,
                                         dst, src, cnt, bucket,
                                         ef, b1, b2, comb);

  // merged conv: even blocks = K (emit ex), odd blocks = V (emit kv rows)
  conv_fused_kernel<<<5000, 512, 0, stream>>>(comb,
                                              W1sw + 0 * 4096, kb1,
                                              Wsw + 0 * 32768, kbr,
                                              Wsw + 1 * 32768, kbl,
                                              W1sw + 1 * 4096, vb1,
                                              Wsw + 2 * 32768, vbr,
                                              Wsw + 3 * 32768, vbl,
                                              qbuf, exb, kvv);

  // attention: vectorized streaming weighted sum via per-node bucket list
  attn_gather_kernel<<<2500, 256, 0, stream>>>(exb, kvv, cnt, bucket, outp);
}

// Round 14
// 209.746 us; speedup vs baseline: 1.1980x; 1.0436x over previous
//
#include <hip/hip_runtime.h>
#include <hip/hip_bf16.h>
#include <math.h>

// Problem constants
#define NNODES 10000
#define NEDGE  160000
#define BCAP   64          // per-node bucket capacity (max degree ~40 here)
// MULT=16, NL=2, DIM=4, EDGE_DIM=32, HID=128, RANK=8, H=4, HM=4

typedef unsigned short u16;
using bf16x8 = __attribute__((ext_vector_type(8))) short;
using f32x4  = __attribute__((ext_vector_type(4))) float;

static __device__ __forceinline__ u16 f2bf(float x) {
  unsigned u = __float_as_uint(x);
  u += 0x7FFFu + ((u >> 16) & 1u);     // RNE
  return (u16)(u >> 16);
}
static __device__ __forceinline__ float bf2f(u16 h) {
  return __uint_as_float(((unsigned)h) << 16);
}
// packed RNE f32x2 -> bf16x2 (gfx950 v_cvt_pk_bf16_f32 via HIP API)
static __device__ __forceinline__ unsigned pack_bf16(float a, float b) {
  __hip_bfloat162 h = __float22bfloat162_rn(make_float2(a, b));
  return *(unsigned*)&h;               // low = a, high = b
}
// tanh-form gelu: x*sigmoid(x*(1.5957691 + 0.0713548*x^2)); |err| < 5e-4 abs.
static __device__ __forceinline__ float fast_gelu(float x) {
  float y = x * __builtin_fmaf(0.07135481283f, x * x, 1.5957691216f);
  float e = __expf(y);
  return x - x * __builtin_amdgcn_rcpf(e + 1.0f);
}

// ------ mega-setup: fill(8thr/edge) | prep_w | prep_w1 | zero-cnt | q -------
// SESSION LESSONS:
// (r1) 10.9M global f32 atomics = 325MB write-through -> never; 160K int ok.
// (r2-r4, r11) ANY perturbation of the conv body risks the 64->68+ VGPR
//   occupancy cliff (8->4 waves/SIMD, +40us) -> conv main path is FROZEN.
// (r5) no cooperative launch under graph capture.
// (r6) no serial block inside a wide dispatch; no big LDS in one branch.
// (r9) gather vectorization (uint loads, 2-edge/wave) = -13us.
// (r10) fill parallelization = flat. (r12) XCD swizzle: traffic win, time
//   loss on this latency-bound conv -> reverted.
// (r14, this round) dependency graph allows 5 nodes -> 3: cnt-zeroing is a
//   setup branch (precedes bucket atomics by dispatch boundary); bucket-
//   assign rides as tail blocks of the conv dispatch (conv doesn't read it;
//   only gather does).
__global__ void __launch_bounds__(256) setup_kernel(
    const float* __restrict__ kwr, const float* __restrict__ kwl,
    const float* __restrict__ vwr, const float* __restrict__ vwl,
    u16* __restrict__ Wsw,
    const float* __restrict__ kw1, const float* __restrict__ vw1,
    u16* __restrict__ W1sw,
    const float* __restrict__ f, const float* __restrict__ qw,
    const float* __restrict__ qb, float* __restrict__ q,
    const int* __restrict__ dst, const int* __restrict__ src,
    int* __restrict__ cnt,
    const float* __restrict__ ef, const float* __restrict__ b1,
    const float* __restrict__ b2, char* __restrict__ comb) {
  int b = blockIdx.x, tid = threadIdx.x;
  if (b < 5000) {                     // fill: 8 thr/edge, EDGE-ORDER comb
    int e = b * 32 + (tid >> 3);      // 0..159999 exact
    int j8 = tid & 7;
    char* rb = comb + (size_t)e * 192;
    const float* frow = f + (size_t)src[e] * 64;
    const float* be = b1 + (size_t)e * 8;          // (4,2)
    float4 bb0 = *(const float4*)&be[0];           // b[0..3]
    float4 bb1 = *(const float4*)&be[4];           // b[4..7]
    // t rows m = 2*j8, 2*j8+1  (8 threads cover 256B of frow contiguously)
    float4 a = *(const float4*)&frow[(2 * j8) * 4];
    float t0 = a.x * bb0.x + a.y * bb0.z + a.z * bb1.x + a.w * bb1.z;
    float t1 = a.x * bb0.y + a.y * bb0.w + a.z * bb1.y + a.w * bb1.w;
    float4 c = *(const float4*)&frow[(2 * j8 + 1) * 4];
    float t2a = c.x * bb0.x + c.y * bb0.z + c.z * bb1.x + c.w * bb1.z;
    float t3a = c.x * bb0.y + c.y * bb0.w + c.z * bb1.y + c.w * bb1.w;
    *(uint2*)(rb + j8 * 8) = make_uint2(pack_bf16(t0, t1), pack_bf16(t2a, t3a));
    // ef bf16 cast at +64B: thread j8 covers floats j8*4..j8*4+3
    float4 ev = *(const float4*)&ef[(size_t)e * 32 + j8 * 4];
    *(uint2*)(rb + 64 + j8 * 8) =
        make_uint2(pack_bf16(ev.x, ev.y), pack_bf16(ev.z, ev.w));
    // b2 copy at +128B (threads 0-1), dst node at +160B (thread 0)
    if (j8 < 2)
      *(float4*)(rb + 128 + j8 * 16) = *(const float4*)&b2[(size_t)e * 8 + j8 * 4];
    if (j8 == 0)
      *(int*)(rb + 160) = dst[e];
  } else if (b < 5512) {              // prep_w: 512 blocks
    int idx = (b - 5000) * 256 + tid; // 0..131071  (4 slots x 32768)
    int slot = idx >> 15;
    int w = idx & 32767;
    int j = w & 7, lane = (w >> 3) & 63, ks = (w >> 9) & 3, tg = w >> 11;
    int k   = ks * 32 + ((lane >> 4) << 3) + j;
    int col = (tg << 4) + (lane & 15);
    const float* s = (slot == 0) ? kwr : (slot == 1) ? kwl : (slot == 2) ? vwr : vwl;
    Wsw[idx] = f2bf(s[k * 256 + col]);
  } else if (b < 5544) {              // prep_w1: 32 blocks
    int idx = (b - 5512) * 256 + tid; // 0..8191 (2 slots x 4096)
    int slot = idx >> 12;
    int w = idx & 4095;
    int j = w & 7, lane = (w >> 3) & 63, nt = w >> 9;
    int k   = ((lane >> 4) << 3) + j;
    int col = (nt << 4) + (lane & 15);
    const float* s = (slot == 0) ? kw1 : vw1;
    W1sw[idx] = f2bf(s[k * 128 + col]);
  } else if (b < 5584) {              // zero-cnt: 40 blocks (replaces memset)
    int idx = (b - 5544) * 256 + tid;
    if (idx < NNODES) cnt[idx] = 0;
  } else {                            // q: 625 blocks (shortest last)
    int i = (b - 5584) * 256 + tid;   // n*16 + o
    if (i >= NNODES * 16) return;
    int n = i >> 4, o = i & 15;
    const float* frow = f + (size_t)n * 64;
    float o0 = 0.f, o1 = 0.f, o2 = 0.f, o3 = 0.f;
#pragma unroll
    for (int m = 0; m < 16; ++m) {
      float w0 = qw[o * 16 + m];
      float w1 = qw[(16 + o) * 16 + m];
      float4 fv = *(const float4*)&frow[m * 4];
      o0 += w0 * fv.x;
      o1 += w1 * fv.y;
      o2 += w1 * fv.z;
      o3 += w1 * fv.w;
    }
    o0 += qb[o];
    float4 r = make_float4(o0, o1, o2, o3);
    *(float4*)(q + (size_t)i * 4) = r;
  }
}

// ---------------- merged equivariant conv (K and V) + bucket tail -----------
// Main path (blocks 0..4999) VERBATIM round-0/round-10 (84.8us, 64 VGPR,
// 38% occupancy). blockIdx even -> K conv (emits ex=exp(qk/4)); odd -> V
// conv (emits bf16 kv rows). Blocks >= 5000 (313 tail blocks): bucket-
// assign (160K int atomics into cnt/bucket, which conv never reads -- only
// gather does). Early-exit branch precedes the frozen body; GATE: if
// VGPR_Count != 64, revert to the 4-node r13 pipeline.
__global__ void __launch_bounds__(512) conv_fused_kernel(
    const char* __restrict__ comb,
    const u16* __restrict__ w1sw_k, const float* __restrict__ b1h_k,
    const u16* __restrict__ wswr_k, const float* __restrict__ br_k,
    const u16* __restrict__ wswl_k, const float* __restrict__ bl_k,
    const u16* __restrict__ w1sw_v, const float* __restrict__ b1h_v,
    const u16* __restrict__ wswr_v, const float* __restrict__ br_v,
    const u16* __restrict__ wswl_v, const float* __restrict__ bl_v,
    const float* __restrict__ qbuf, float* __restrict__ exs,
    u16* __restrict__ kv,
    const int* __restrict__ dst, int* __restrict__ cnt,
    int* __restrict__ bucket) {
  __shared__ alignas(16) u16 sA[64 * 136];    // H tile [edge][hid]
  __shared__ alignas(16) u16 t_s[64 * 40];    // t tile (bf16)
  __shared__ alignas(16) float b2_s[64 * 12];
  __shared__ alignas(16) float u_s[64 * 12];  // u[e][p]
  __shared__ alignas(16) float t2_pool[64 * 36]; // t2[e][r2]; overlays efs
  float* t2_s = t2_pool;
  u16*   efs  = (u16*)t2_pool;                // ef tile bf16 [edge][k] pitch 40

  int tid = threadIdx.x;
  if (blockIdx.x >= 5000) {                   // bucket-assign tail: 313 blocks
    int e = (blockIdx.x - 5000) * 512 + tid;  // 313*512 = 160256
    if (e < NEDGE) {
      int n = dst[e];
      int pos = atomicAdd(&cnt[n], 1);        // cnt zeroed by setup branch
      bucket[n * BCAP + pos] = e;
    }
    return;
  }
  int wave = tid >> 6, lane = tid & 63, quad = lane >> 4, l16 = lane & 15;
  bool kmode = (blockIdx.x & 1) == 0;
  size_t i0 = (size_t)(blockIdx.x >> 1) * 64;

  const u16*   w1sw = kmode ? w1sw_k : w1sw_v;
  const float* b1h  = kmode ? b1h_k  : b1h_v;
  const u16*   wsw_r = kmode ? wswr_k : wswr_v;
  const float* br    = kmode ? br_k   : br_v;
  const u16*   wsw_l = kmode ? wswl_k : wswl_v;
  const float* bl    = kmode ? bl_k   : bl_v;

  // ---- stage tiles from comb ----
  if (tid < 256) {            // ef tile: 64 rows x 64B at +64
    int row = tid >> 2, seg = tid & 3;
    *(uint4*)&efs[row * 40 + seg * 8] =
        *(const uint4*)(comb + (i0 + row) * 192 + 64 + seg * 16);
    if (tid < 128) {          // b2 tile: 64 rows x 32B at +128
      int r2 = tid >> 1, half = tid & 1;
      *(float4*)&b2_s[r2 * 12 + half * 4] =
          *(const float4*)(comb + (i0 + r2) * 192 + 128 + half * 16);
    }
  } else {                    // t tile: 64 rows x 64B at +0
    int j = tid - 256;
    int row = j >> 2, seg = j & 3;
    *(uint4*)&t_s[row * 40 + seg * 8] =
        *(const uint4*)(comb + (i0 + row) * 192 + seg * 16);
  }
  __syncthreads();

  // ---- h-stage: wave owns hid-tile `wave` (16 cols), 4 edge tiles ----
  {
    bf16x8 aw = *(const bf16x8*)&w1sw[(size_t)(wave * 64 + lane) * 8];  // A = w1^T
    float4 bias_h = *(const float4*)&b1h[wave * 16 + quad * 4];
#pragma unroll
    for (int nt = 0; nt < 4; ++nt) {
      bf16x8 be = *(const bf16x8*)&efs[(nt * 16 + l16) * 40 + quad * 8]; // B = ef^T
      f32x4 acch = __builtin_amdgcn_mfma_f32_16x16x32_bf16(aw, be, (f32x4){0.f, 0.f, 0.f, 0.f}, 0, 0, 0);
      unsigned p0 = pack_bf16(fast_gelu(acch[0] + bias_h.x), fast_gelu(acch[1] + bias_h.y));
      unsigned p1 = pack_bf16(fast_gelu(acch[2] + bias_h.z), fast_gelu(acch[3] + bias_h.w));
      *(uint2*)&sA[(nt * 16 + l16) * 136 + wave * 16 + quad * 4] = make_uint2(p0, p1);
    }
  }
  __syncthreads();

  // ---- K-loop: transposed GEMMs (A = weights, B = H), zero-seeded accs ----
  f32x4 accr[2][4], accl[2][4];
#pragma unroll
  for (int mtl = 0; mtl < 2; ++mtl)
#pragma unroll
    for (int nt = 0; nt < 4; ++nt) {
      accr[mtl][nt] = (f32x4){0.f, 0.f, 0.f, 0.f};
      accl[mtl][nt] = (f32x4){0.f, 0.f, 0.f, 0.f};
    }
#pragma unroll
  for (int ks = 0; ks < 4; ++ks) {
    bf16x8 bfrag[4];
#pragma unroll
    for (int nt = 0; nt < 4; ++nt)
      bfrag[nt] = *(const bf16x8*)&sA[(nt * 16 + l16) * 136 + ks * 32 + quad * 8];
#pragma unroll
    for (int mtl = 0; mtl < 2; ++mtl) {
      int mtg = wave * 2 + mtl;
      bf16x8 ar = *(const bf16x8*)&wsw_r[(size_t)((mtg * 4 + ks) * 64 + lane) * 8];
      bf16x8 al = *(const bf16x8*)&wsw_l[(size_t)((mtg * 4 + ks) * 64 + lane) * 8];
#pragma unroll
      for (int nt = 0; nt < 4; ++nt) {
        accr[mtl][nt] = __builtin_amdgcn_mfma_f32_16x16x32_bf16(ar, bfrag[nt], accr[mtl][nt], 0, 0, 0);
        accl[mtl][nt] = __builtin_amdgcn_mfma_f32_16x16x32_bf16(al, bfrag[nt], accl[mtl][nt], 0, 0, 0);
      }
    }
  }

  // ---- bias preloads: weight-col = (2w+mtl)*16 + 4q + r ----
  float4 brv[2], blv[2];
#pragma unroll
  for (int mtl = 0; mtl < 2; ++mtl) {
    int colb = (wave * 2 + mtl) * 16 + quad * 4;
    brv[mtl] = *(const float4*)&br[colb];
    blv[mtl] = *(const float4*)&bl[colb];
  }

  // ---- right epilogue: u[e, p=wave] = sum_c (right+br)*t ----
#pragma unroll
  for (int nt = 0; nt < 4; ++nt) {
    int e = nt * 16 + l16;
    ushort4 ta = *(const ushort4*)&t_s[e * 40 + 4 * quad];        // c: mtl=0
    ushort4 tb = *(const ushort4*)&t_s[e * 40 + 16 + 4 * quad];   // c: mtl=1
    float s = (accr[0][nt][0] + brv[0].x) * bf2f(ta.x)
            + (accr[0][nt][1] + brv[0].y) * bf2f(ta.y)
            + (accr[0][nt][2] + brv[0].z) * bf2f(ta.z)
            + (accr[0][nt][3] + brv[0].w) * bf2f(ta.w)
            + (accr[1][nt][0] + brv[1].x) * bf2f(tb.x)
            + (accr[1][nt][1] + brv[1].y) * bf2f(tb.y)
            + (accr[1][nt][2] + brv[1].z) * bf2f(tb.z)
            + (accr[1][nt][3] + brv[1].w) * bf2f(tb.w);
    s += __shfl_xor(s, 16);
    s += __shfl_xor(s, 32);
    if (quad == 0) u_s[e * 12 + wave] = s;
  }
  __syncthreads();   // u_s ready; efs reads long done -> t2_s overlay safe

  // ---- left epilogue: t2[e, r2] = sum_p (left+bl)*u ----
#pragma unroll
  for (int nt = 0; nt < 4; ++nt) {
    int e = nt * 16 + l16;
    float4 uv = *(const float4*)&u_s[e * 12 + 4 * (quad & 1)];
#pragma unroll
    for (int mtl = 0; mtl < 2; ++mtl) {
      float s = (accl[mtl][nt][0] + blv[mtl].x) * uv.x
              + (accl[mtl][nt][1] + blv[mtl].y) * uv.y
              + (accl[mtl][nt][2] + blv[mtl].z) * uv.z
              + (accl[mtl][nt][3] + blv[mtl].w) * uv.w;
      s += __shfl_xor(s, 16);                    // combine p halves (q^1)
      if ((quad & 1) == 0)
        t2_s[e * 36 + 4 * wave + 2 * mtl + (quad >> 1)] = s;
    }
  }
  __syncthreads();

  // ---- final stage: thread -> (e = tid>>3, j = tid&7), elems j*8..j*8+7 ----
  {
    int e = tid >> 3, j = tid & 7;
    float4 t2 = *(const float4*)&t2_s[e * 36 + 4 * j];   // r2 = 4j..4j+3
    float4 b2a = *(const float4*)&b2_s[e * 12 + 0];
    float4 b2b = *(const float4*)&b2_s[e * 12 + 4];
    float v0 = t2.x * b2a.x + t2.y * b2b.x;   // m=2j,   d=0..3
    float v1 = t2.x * b2a.y + t2.y * b2b.y;
    float v2 = t2.x * b2a.z + t2.y * b2b.z;
    float v3 = t2.x * b2a.w + t2.y * b2b.w;
    float v4 = t2.z * b2a.x + t2.w * b2b.x;   // m=2j+1, d=0..3
    float v5 = t2.z * b2a.y + t2.w * b2b.y;
    float v6 = t2.z * b2a.z + t2.w * b2b.z;
    float v7 = t2.z * b2a.w + t2.w * b2b.w;
    if (kmode) {
      // K mode: head (j>>1) half-dot with q, pair-combine, exp, store ex
      int n = *(const int*)(comb + (i0 + e) * 192 + 160);
      const float* qr = qbuf + (size_t)n * 64 + j * 8;
      float4 qa = *(const float4*)&qr[0];
      float4 qc = *(const float4*)&qr[4];
      float s = v0 * qa.x + v1 * qa.y + v2 * qa.z + v3 * qa.w
              + v4 * qc.x + v5 * qc.y + v6 * qc.z + v7 * qc.w;
      s += __shfl_xor(s, 1);                     // combine the two half-heads
      if ((j & 1) == 0)
        exs[(i0 + e) * 4 + (j >> 1)] = __expf(s * 0.25f);
    } else {
      // V mode: pack bf16 kv row
      unsigned q0 = pack_bf16(v0, v1);
      unsigned q1 = pack_bf16(v2, v3);
      unsigned q2 = pack_bf16(v4, v5);
      unsigned q3 = pack_bf16(v6, v7);
      *(uint4*)&kv[(i0 + e) * 64 + j * 8] = make_uint4(q0, q1, q2, q3);
    }
  }
}

// ---------------- attention gather: vectorized two-edge-per-wave ------------
// lanes 0-31 = edge A, lanes 32-63 = edge B; each lane loads one uint
// (2 bf16 = output positions 2*l32, 2*l32+1). Halves combined with
// shfl_xor(32); den per-head (head = l32>>3). (r9: validated, -13us)
__global__ void __launch_bounds__(256) attn_gather_kernel(
    const float* __restrict__ exs, const u16* __restrict__ kvv,
    const int* __restrict__ cnt, const int* __restrict__ bucket,
    float* __restrict__ outp) {
  int tid = threadIdx.x;
  int node = blockIdx.x * 4 + (tid >> 6);        // grid 2500 * 4 = NNODES
  int lane = tid & 63;
  int half = lane >> 5;                          // 0: edge A, 1: edge B
  int l32 = lane & 31;                           // covers elems 2*l32, 2*l32+1
  int h = l32 >> 3;                              // head of both elems
  int end = cnt[node];
  const int* bk = bucket + (size_t)node * BCAP;
  float nx = 0.f, ny = 0.f, den = 0.f;
  int idx = 0;
  for (; idx + 4 <= end; idx += 4) {             // 4 edges: 2 indep chains
    int e0 = bk[idx + half];
    int e1 = bk[idx + 2 + half];
    float x0 = exs[(size_t)e0 * 4 + h];
    float x1 = exs[(size_t)e1 * 4 + h];
    unsigned p0 = *(const unsigned*)&kvv[(size_t)e0 * 64 + l32 * 2];
    unsigned p1 = *(const unsigned*)&kvv[(size_t)e1 * 64 + l32 * 2];
    nx += x0 * bf2f((u16)(p0 & 0xFFFF)) + x1 * bf2f((u16)(p1 & 0xFFFF));
    ny += x0 * bf2f((u16)(p0 >> 16))    + x1 * bf2f((u16)(p1 >> 16));
    den += x0 + x1;
  }
  for (; idx + 2 <= end; idx += 2) {             // 2 edges
    int e0 = bk[idx + half];
    float x0 = exs[(size_t)e0 * 4 + h];
    unsigned p0 = *(const unsigned*)&kvv[(size_t)e0 * 64 + l32 * 2];
    nx += x0 * bf2f((u16)(p0 & 0xFFFF));
    ny += x0 * bf2f((u16)(p0 >> 16));
    den += x0;
  }
  if (idx < end && half == 0) {                  // odd tail: half A only
    int e0 = bk[idx];
    float x0 = exs[(size_t)e0 * 4 + h];
    unsigned p0 = *(const unsigned*)&kvv[(size_t)e0 * 64 + l32 * 2];
    nx += x0 * bf2f((u16)(p0 & 0xFFFF));
    ny += x0 * bf2f((u16)(p0 >> 16));
    den += x0;
  }
  // combine the two half-wave edge streams
  nx  += __shfl_xor(nx, 32);
  ny  += __shfl_xor(ny, 32);
  den += __shfl_xor(den, 32);
  if (half == 0) {
    float r = 1.0f / fmaxf(den, 1e-9f);
    float2 o = make_float2(nx * r, ny * r);
    *(float2*)&outp[(size_t)node * 64 + l32 * 2] = o;
  }
}

extern "C" void kernel_launch(void* const* d_in, const int* in_sizes, int n_in,
                              void* d_out, int out_size, void* d_ws, size_t ws_size,
                              hipStream_t stream) {
  const float* b1  = (const float*)d_in[0];
  const float* b2  = (const float*)d_in[1];
  const float* ef  = (const float*)d_in[2];
  const float* f   = (const float*)d_in[3];
  const int*   src = (const int*)d_in[4];
  const int*   dst = (const int*)d_in[5];
  const float* qw  = (const float*)d_in[6];
  const float* qb  = (const float*)d_in[7];
  const float* kw1 = (const float*)d_in[8];
  const float* kb1 = (const float*)d_in[9];
  const float* kwl = (const float*)d_in[10];
  const float* kbl = (const float*)d_in[11];
  const float* kwr = (const float*)d_in[12];
  const float* kbr = (const float*)d_in[13];
  const float* vw1 = (const float*)d_in[14];
  const float* vb1 = (const float*)d_in[15];
  const float* vwl = (const float*)d_in[16];
  const float* vbl = (const float*)d_in[17];
  const float* vwr = (const float*)d_in[18];
  const float* vbr = (const float*)d_in[19];
  float* outp = (float*)d_out;

  // workspace layout
  char* ws = (char*)d_ws;
  size_t off = 0;
  auto alloc = [&](size_t bytes) {
    char* p = ws + off;
    off += (bytes + 511) & ~(size_t)511;
    return p;
  };
  u16*   Wsw  = (u16*)  alloc((size_t)4 * 32768 * 2);
  u16*   W1sw = (u16*)  alloc((size_t)2 * 4096 * 2);
  char*  comb = (char*) alloc((size_t)NEDGE * 192);
  u16*   kvv  = (u16*)  alloc((size_t)NEDGE * 64 * 2);
  float* exb  = (float*)alloc((size_t)NEDGE * 4 * 4);
  float* qbuf = (float*)alloc((size_t)NNODES * 64 * 4);
  int*   cnt    = (int*)alloc((size_t)NNODES * 4);
  int*   bucket = (int*)alloc((size_t)NNODES * BCAP * 4);

  // 3-node pipeline: setup (incl. cnt zeroing) -> conv (incl. bucket tail)
  // -> gather.
  setup_kernel<<<6209, 256, 0, stream>>>(kwr, kwl, vwr, vwl, Wsw,
                                         kw1, vw1, W1sw,
                                         f, qw, qb, qbuf,
                                         dst, src, cnt,
                                         ef, b1, b2, comb);

  // merged conv (blocks 0-4999: even = K, odd = V) + bucket-assign tail
  // (blocks 5000-5312)
  conv_fused_kernel<<<5313, 512, 0, stream>>>(comb,
                                              W1sw + 0 * 4096, kb1,
                                              Wsw + 0 * 32768, kbr,
                                              Wsw + 1 * 32768, kbl,
                                              W1sw + 1 * 4096, vb1,
                                              Wsw + 2 * 32768, vbr,
                                              Wsw + 3 * 32768, vbl,
                                              qbuf, exb, kvv,
                                              dst, cnt, bucket);

  // attention: vectorized streaming weighted sum via per-node bucket list
  attn_gather_kernel<<<2500, 256, 0, stream>>>(exb, kvv, cnt, bucket, outp);
}